// Round 3
// baseline (135.599 us; speedup 1.0000x reference)
//
#include <hip/hip_runtime.h>

#define S_LEN 2048
#define E_DIM 512
#define NTOK  16384   // B*S = 8*2048

typedef __bf16 bf16x8_t __attribute__((ext_vector_type(8)));
typedef float f32x4_t __attribute__((ext_vector_type(4)));
typedef unsigned short u16x8_t __attribute__((ext_vector_type(8)));

__device__ __forceinline__ unsigned short f2bf(float f) {
  unsigned u = __float_as_uint(f);
  u += 0x7FFFu + ((u >> 16) & 1u);   // round-to-nearest-even
  return (unsigned short)(u >> 16);
}
__device__ __forceinline__ float bf2f(unsigned short h) {
  return __uint_as_float(((unsigned)h) << 16);
}
// native casts -> compiler emits v_cvt_pk_bf16_f32 (hot path)
__device__ __forceinline__ u16x8_t cvt8n(float4 a, float4 b) {
  bf16x8_t t;
  t[0] = (__bf16)a.x; t[1] = (__bf16)a.y; t[2] = (__bf16)a.z; t[3] = (__bf16)a.w;
  t[4] = (__bf16)b.x; t[5] = (__bf16)b.y; t[6] = (__bf16)b.z; t[7] = (__bf16)b.w;
  union { bf16x8_t h; u16x8_t u; } cv; cv.h = t; return cv.u;
}

// ---------------- offsets -> gather indices (fp32, must match ref closely) ----------------
__global__ __launch_bounds__(256)
void offsets_kernel(const float* __restrict__ q, const float* __restrict__ ow,
                    const float* __restrict__ ob, int* __restrict__ idx)
{
  const int wid  = threadIdx.x >> 6;
  const int lane = threadIdx.x & 63;
  const int n = blockIdx.x * 4 + wid;          // token
  const int s = n & (S_LEN - 1);
  const float* qr = q + (size_t)n * E_DIM + lane * 8;
  const float4 q0 = *(const float4*)qr;
  const float4 q1 = *(const float4*)(qr + 4);
  float myoff = 0.f;
  #pragma unroll
  for (int p = 0; p < 8; ++p) {
    const float* wr = ow + (size_t)(2 * p) * E_DIM + lane * 8;   // row 2p = offsets[...,0]
    const float4 w0 = *(const float4*)wr;
    const float4 w1 = *(const float4*)(wr + 4);
    float acc = q0.x*w0.x + q0.y*w0.y + q0.z*w0.z + q0.w*w0.w
              + q1.x*w1.x + q1.y*w1.y + q1.z*w1.z + q1.w*w1.w;
    #pragma unroll
    for (int d = 32; d; d >>= 1) acc += __shfl_xor(acc, d, 64);
    if ((lane & 7) == p) myoff = acc;
  }
  if (lane < 8) {
    float off = myoff + ob[2 * lane];
    float val = (float)s + off;
    int id = (int)truncf(val);                 // trunc toward zero, then clip (matches ref)
    id = id < 0 ? 0 : (id > S_LEN - 1 ? S_LEN - 1 : id);
    idx[n * 8 + lane] = id;
  }
}

// ---------------- bf16 MFMA GEMM: C(16384 x 512) = A @ W^T + bias ----------------
// 256x128 block tile, BK=64, 8 waves (4x2) of 64x64 wave tiles, XOR-swizzled LDS,
// double-buffered (96 KB), native cvt_pk conversions, one barrier per K-step.
template<int A_BF16, int OUT_BF16>
__global__ __launch_bounds__(512, 2)
void gemm_kernel(const void* __restrict__ A0v, const void* __restrict__ A1v,
                 const void* __restrict__ A2v, const float* __restrict__ W,
                 const float* __restrict__ bias, void* __restrict__ Cout)
{
  __shared__ __align__(16) unsigned short sA[2][256 * 64];   // 64 KB
  __shared__ __align__(16) unsigned short sB[2][128 * 64];   // 32 KB

  const int z = blockIdx.z;
  const void* Av = (z == 0) ? A0v : ((z == 1) ? A1v : A2v);
  const float* Af = (const float*)Av;
  const unsigned short* Ab = (const unsigned short*)Av;
  const float* Wz = W + (size_t)z * E_DIM * E_DIM;
  const float* bz = bias + (size_t)z * E_DIM;

  const int t    = threadIdx.x;
  const int lane = t & 63;
  const int wid  = t >> 6;        // 0..7
  const int wm   = wid >> 1;      // 0..3  (64-row quarter of 256)
  const int wn   = wid & 1;       // 0..1  (64-col half of 128)
  const size_t m0 = (size_t)blockIdx.y * 256;
  const size_t n0 = (size_t)blockIdx.x * 128;

  // staging: A = 256x64 in 1024 16-elem chunks (thread t -> chunks t, t+512)
  //          B = 128x64 in 512 chunks (thread t -> chunk t)
  const int srow  = t >> 2;           // 0..127
  const int scolf = (t & 3) * 16;     // 0/16/32/48
  const int sswz  = (srow & 7) << 3;
  const int se0   = srow * 64 + (scolf ^ sswz);
  const int se1   = srow * 64 + ((scolf + 8) ^ sswz);

  f32x4_t acc[4][4];
  #pragma unroll
  for (int i = 0; i < 4; ++i)
    #pragma unroll
    for (int j = 0; j < 4; ++j)
      acc[i][j] = (f32x4_t){0.f, 0.f, 0.f, 0.f};

  float4 arf[8], brf[4];
  u16x8_t arb[4];

#define LOAD_T(k0) do { \
    if constexpr (A_BF16) { \
      const unsigned short* ap0 = Ab + (m0 + (size_t)srow) * E_DIM + (k0) + scolf; \
      arb[0] = *(const u16x8_t*)ap0; arb[1] = *(const u16x8_t*)(ap0 + 8); \
      const unsigned short* ap1 = ap0 + (size_t)128 * E_DIM; \
      arb[2] = *(const u16x8_t*)ap1; arb[3] = *(const u16x8_t*)(ap1 + 8); \
    } else { \
      const float* ap0 = Af + (m0 + (size_t)srow) * E_DIM + (k0) + scolf; \
      arf[0] = *(const float4*)ap0;        arf[1] = *(const float4*)(ap0 + 4); \
      arf[2] = *(const float4*)(ap0 + 8);  arf[3] = *(const float4*)(ap0 + 12); \
      const float* ap1 = ap0 + (size_t)128 * E_DIM; \
      arf[4] = *(const float4*)ap1;        arf[5] = *(const float4*)(ap1 + 4); \
      arf[6] = *(const float4*)(ap1 + 8);  arf[7] = *(const float4*)(ap1 + 12); \
    } \
    const float* bp = Wz + (n0 + (size_t)srow) * E_DIM + (k0) + scolf; \
    brf[0] = *(const float4*)bp;        brf[1] = *(const float4*)(bp + 4); \
    brf[2] = *(const float4*)(bp + 8);  brf[3] = *(const float4*)(bp + 12); \
  } while (0)

#define STORE_T(buf) do { \
    if constexpr (A_BF16) { \
      *(u16x8_t*)&sA[buf][se0]        = arb[0]; \
      *(u16x8_t*)&sA[buf][se1]        = arb[1]; \
      *(u16x8_t*)&sA[buf][se0 + 8192] = arb[2]; \
      *(u16x8_t*)&sA[buf][se1 + 8192] = arb[3]; \
    } else { \
      *(u16x8_t*)&sA[buf][se0]        = cvt8n(arf[0], arf[1]); \
      *(u16x8_t*)&sA[buf][se1]        = cvt8n(arf[2], arf[3]); \
      *(u16x8_t*)&sA[buf][se0 + 8192] = cvt8n(arf[4], arf[5]); \
      *(u16x8_t*)&sA[buf][se1 + 8192] = cvt8n(arf[6], arf[7]); \
    } \
    *(u16x8_t*)&sB[buf][se0] = cvt8n(brf[0], brf[1]); \
    *(u16x8_t*)&sB[buf][se1] = cvt8n(brf[2], brf[3]); \
  } while (0)

  LOAD_T(0);
  STORE_T(0);
  int cur = 0;

  const int fswz = (lane & 7) << 3;
  const int kb   = (lane >> 4) * 8;
  const int fr   = lane & 15;

  for (int kt = 0; kt < 8; ++kt) {            // 512 / 64
    __syncthreads();                          // staged tile (cur) visible
    if (kt < 7) LOAD_T((kt + 1) * 64);        // next-tile global loads hide under MFMA
    #pragma unroll
    for (int kk = 0; kk < 64; kk += 32) {
      bf16x8_t af[4], bfv[4];
      #pragma unroll
      for (int i = 0; i < 4; ++i)
        af[i] = *(const bf16x8_t*)&sA[cur][(wm * 64 + i * 16 + fr) * 64 + ((kk + kb) ^ fswz)];
      #pragma unroll
      for (int j = 0; j < 4; ++j)
        bfv[j] = *(const bf16x8_t*)&sB[cur][(wn * 64 + j * 16 + fr) * 64 + ((kk + kb) ^ fswz)];
      #pragma unroll
      for (int i = 0; i < 4; ++i)
        #pragma unroll
        for (int j = 0; j < 4; ++j)
          acc[i][j] = __builtin_amdgcn_mfma_f32_16x16x32_bf16(af[i], bfv[j], acc[i][j], 0, 0, 0);
    }
    if (kt < 7) STORE_T(cur ^ 1);             // cvt + ds_write next buffer
    cur ^= 1;
  }
#undef LOAD_T
#undef STORE_T

  // Epilogue: D row = (lane>>4)*4 + r, col = lane&15  (m89-verified C/D layout)
  unsigned short* Cb = (unsigned short*)Cout + (size_t)z * NTOK * E_DIM;
  float* Cf = (float*)Cout;
  #pragma unroll
  for (int i = 0; i < 4; ++i) {
    const int row = (int)m0 + wm * 64 + i * 16 + (lane >> 4) * 4;
    #pragma unroll
    for (int j = 0; j < 4; ++j) {
      const int col = (int)n0 + wn * 64 + j * 16 + fr;
      const float bv = bz[col];
      #pragma unroll
      for (int r = 0; r < 4; ++r) {
        const float val = acc[i][j][r] + bv;
        if constexpr (OUT_BF16)
          Cb[(size_t)(row + r) * E_DIM + col] = f2bf(val);
        else
          Cf[(size_t)(row + r) * E_DIM + col] = val;
      }
    }
  }
}

// ---------------- attention: gather projected rows, softmax over P=8, ctx (bf16) ----------------
__global__ __launch_bounds__(256)
void attn_kernel(const unsigned short* __restrict__ Qp, const unsigned short* __restrict__ Kp,
                 const unsigned short* __restrict__ Vp, const int* __restrict__ idx,
                 unsigned short* __restrict__ ctx)
{
  const int wid  = threadIdx.x >> 6;
  const int lane = threadIdx.x & 63;
  const int n = blockIdx.x * 4 + wid;
  const int b = n >> 11;
  const int h = lane >> 3;
  const int p = lane & 7;

  const int id = idx[n * 8 + p];
  const size_t krow = ((size_t)(b << 11) + id) * E_DIM + h * 64;
  const unsigned short* qb = Qp + (size_t)n * E_DIM + h * 64;

  float sc = 0.f;
  #pragma unroll
  for (int j = 0; j < 8; ++j) {
    u16x8_t qv = *(const u16x8_t*)(qb + j * 8);
    u16x8_t kv = *(const u16x8_t*)(Kp + krow + j * 8);
    #pragma unroll
    for (int e = 0; e < 8; ++e) sc += bf2f(qv[e]) * bf2f(kv[e]);
  }
  sc *= 0.125f;  // 1/sqrt(64)

  float m = sc;
  m = fmaxf(m, __shfl_xor(m, 1, 64));
  m = fmaxf(m, __shfl_xor(m, 2, 64));
  m = fmaxf(m, __shfl_xor(m, 4, 64));
  const float ex = __expf(sc - m);
  float dsum = ex;
  dsum += __shfl_xor(dsum, 1, 64);
  dsum += __shfl_xor(dsum, 2, 64);
  dsum += __shfl_xor(dsum, 4, 64);
  const float attn = ex / dsum;

  // phase 2: lane -> (h, d-block p*8); ctx[h][d] = sum_p attn[h][p] * Vp[idx_p][h*64+d]
  const int d0 = p * 8;
  float cacc[8];
  #pragma unroll
  for (int j = 0; j < 8; ++j) cacc[j] = 0.f;
  #pragma unroll
  for (int pp = 0; pp < 8; ++pp) {
    const float ap = __shfl(attn, (lane & 56) + pp, 64);
    const int  idp = __shfl(id,   (lane & 56) + pp, 64);
    const unsigned short* vb = Vp + ((size_t)(b << 11) + idp) * E_DIM + h * 64 + d0;
    u16x8_t vv = *(const u16x8_t*)vb;
    #pragma unroll
    for (int j = 0; j < 8; ++j) cacc[j] += ap * bf2f(vv[j]);
  }
  u16x8_t cc;
  #pragma unroll
  for (int j = 0; j < 8; ++j) cc[j] = f2bf(cacc[j]);
  *(u16x8_t*)(ctx + (size_t)n * E_DIM + h * 64 + d0) = cc;
}

extern "C" void kernel_launch(void* const* d_in, const int* in_sizes, int n_in,
                              void* d_out, int out_size, void* d_ws, size_t ws_size,
                              hipStream_t stream) {
  const float* q        = (const float*)d_in[0];
  const float* k        = (const float*)d_in[1];
  const float* v        = (const float*)d_in[2];
  const float* offset_w = (const float*)d_in[3];
  const float* offset_b = (const float*)d_in[4];
  const float* in_proj_w = (const float*)d_in[5];
  const float* in_proj_b = (const float*)d_in[6];
  const float* out_w    = (const float*)d_in[7];
  const float* out_b    = (const float*)d_in[8];

  char* ws = (char*)d_ws;
  // layout: Qp|Kp|Vp|ctx bf16 (4 * 16384*512*2 = 67.1MB), idx (512KB)
  unsigned short* Qp   = (unsigned short*)ws;
  unsigned short* Kp   = Qp + (size_t)NTOK * E_DIM;
  unsigned short* Vp   = Kp + (size_t)NTOK * E_DIM;
  unsigned short* ctxb = Vp + (size_t)NTOK * E_DIM;
  int* idxb = (int*)(ws + (size_t)4 * NTOK * E_DIM * 2);

  offsets_kernel<<<NTOK / 4, 256, 0, stream>>>(q, offset_w, offset_b, idxb);
  gemm_kernel<0, 1><<<dim3(E_DIM / 128, NTOK / 256, 3), 512, 0, stream>>>(
      q, k, v, in_proj_w, in_proj_b, (void*)Qp);
  attn_kernel<<<NTOK / 4, 256, 0, stream>>>(Qp, Kp, Vp, idxb, ctxb);
  gemm_kernel<1, 0><<<dim3(E_DIM / 128, NTOK / 256, 1), 512, 0, stream>>>(
      ctxb, ctxb, ctxb, out_w, out_b, d_out);
}

// Round 4
// 119.336 us; speedup vs baseline: 1.1363x; 1.1363x over previous
//
#include <hip/hip_runtime.h>

#define S_LEN 2048
#define E_DIM 512
#define NTOK  16384   // B*S = 8*2048

typedef __bf16 bf16x8_t __attribute__((ext_vector_type(8)));
typedef float f32x4_t __attribute__((ext_vector_type(4)));
typedef unsigned short u16x8_t __attribute__((ext_vector_type(8)));

__device__ __forceinline__ float bf2f(unsigned short h) {
  return __uint_as_float(((unsigned)h) << 16);
}
// native casts -> compiler emits v_cvt_pk_bf16_f32 (m240: don't hand-roll)
__device__ __forceinline__ u16x8_t cvt8n(float4 a, float4 b) {
  bf16x8_t t;
  t[0] = (__bf16)a.x; t[1] = (__bf16)a.y; t[2] = (__bf16)a.z; t[3] = (__bf16)a.w;
  t[4] = (__bf16)b.x; t[5] = (__bf16)b.y; t[6] = (__bf16)b.z; t[7] = (__bf16)b.w;
  union { bf16x8_t h; u16x8_t u; } cv; cv.h = t; return cv.u;
}

// ---------------- offsets -> gather indices (fp32, must match ref closely) ----------------
__global__ __launch_bounds__(256)
void offsets_kernel(const float* __restrict__ q, const float* __restrict__ ow,
                    const float* __restrict__ ob, int* __restrict__ idx)
{
  const int wid  = threadIdx.x >> 6;
  const int lane = threadIdx.x & 63;
  const int n = blockIdx.x * 4 + wid;          // token
  const int s = n & (S_LEN - 1);
  const float* qr = q + (size_t)n * E_DIM + lane * 8;
  const float4 q0 = *(const float4*)qr;
  const float4 q1 = *(const float4*)(qr + 4);
  float myoff = 0.f;
  #pragma unroll
  for (int p = 0; p < 8; ++p) {
    const float* wr = ow + (size_t)(2 * p) * E_DIM + lane * 8;   // row 2p = offsets[...,0]
    const float4 w0 = *(const float4*)wr;
    const float4 w1 = *(const float4*)(wr + 4);
    float acc = q0.x*w0.x + q0.y*w0.y + q0.z*w0.z + q0.w*w0.w
              + q1.x*w1.x + q1.y*w1.y + q1.z*w1.z + q1.w*w1.w;
    #pragma unroll
    for (int d = 32; d; d >>= 1) acc += __shfl_xor(acc, d, 64);
    if ((lane & 7) == p) myoff = acc;
  }
  if (lane < 8) {
    float off = myoff + ob[2 * lane];
    float val = (float)s + off;
    int id = (int)truncf(val);                 // trunc toward zero, then clip (matches ref)
    id = id < 0 ? 0 : (id > S_LEN - 1 ? S_LEN - 1 : id);
    idx[n * 8 + lane] = id;
  }
}

// ---------------- bf16 MFMA GEMM: C(16384 x 512) = A @ W^T + bias ----------------
// 128x128 tile, BK=64, 8 waves (2x4) of 64x32 wave tiles, XOR-swizzled LDS,
// double-buffered 64 KB (2 blocks/CU), native cvt_pk, one barrier per K-step.
// Grid MUST be (m-tile, n-tile, z): same-m blocks are 128 apart -> same XCD -> A L2-reuse.
template<int A_BF16, int OUT_BF16>
__global__ __launch_bounds__(512, 4)
void gemm_kernel(const void* __restrict__ A0v, const void* __restrict__ A1v,
                 const void* __restrict__ A2v, const float* __restrict__ W,
                 const float* __restrict__ bias, void* __restrict__ Cout)
{
  __shared__ __align__(16) unsigned short sA[2][128 * 64];
  __shared__ __align__(16) unsigned short sB[2][128 * 64];

  const int z = blockIdx.z;
  const void* Av = (z == 0) ? A0v : ((z == 1) ? A1v : A2v);
  const float* Af = (const float*)Av;
  const unsigned short* Ab = (const unsigned short*)Av;
  const float* Wz = W + (size_t)z * E_DIM * E_DIM;
  const float* bz = bias + (size_t)z * E_DIM;

  const int t    = threadIdx.x;
  const int lane = t & 63;
  const int wid  = t >> 6;        // 0..7
  const int wm   = wid >> 2;      // 0..1  (64-row half)
  const int wn   = wid & 3;       // 0..3  (32-col quarter)
  const size_t m0 = (size_t)blockIdx.x * 128;
  const size_t n0 = (size_t)blockIdx.y * 128;

  const int srow = t >> 2;        // 0..127 staged row
  const int scol = (t & 3) * 16;  // staged col (elements)
  const int swzE = (srow & 7) << 3;           // element-XOR (== byte ^ (row&7)<<4)
  const int se0  = srow * 64 + (scol ^ swzE);
  const int se1  = srow * 64 + ((scol + 8) ^ swzE);

  f32x4_t acc[4][2];
  #pragma unroll
  for (int i = 0; i < 4; ++i)
    #pragma unroll
    for (int j = 0; j < 2; ++j)
      acc[i][j] = (f32x4_t){0.f, 0.f, 0.f, 0.f};

  float4 arf[4], brf[4];
  u16x8_t arb[2];

#define LOAD_T(k0) do { \
    const float* bp = Wz + (n0 + (size_t)srow) * E_DIM + (k0) + scol; \
    brf[0] = *(const float4*)bp;       brf[1] = *(const float4*)(bp + 4); \
    brf[2] = *(const float4*)(bp + 8); brf[3] = *(const float4*)(bp + 12); \
    if constexpr (A_BF16) { \
      const unsigned short* ap = Ab + (m0 + (size_t)srow) * E_DIM + (k0) + scol; \
      arb[0] = *(const u16x8_t*)ap; arb[1] = *(const u16x8_t*)(ap + 8); \
    } else { \
      const float* ap = Af + (m0 + (size_t)srow) * E_DIM + (k0) + scol; \
      arf[0] = *(const float4*)ap;       arf[1] = *(const float4*)(ap + 4); \
      arf[2] = *(const float4*)(ap + 8); arf[3] = *(const float4*)(ap + 12); \
    } } while (0)

#define STORE_T(buf) do { \
    if constexpr (A_BF16) { \
      *(u16x8_t*)&sA[buf][se0] = arb[0]; \
      *(u16x8_t*)&sA[buf][se1] = arb[1]; \
    } else { \
      *(u16x8_t*)&sA[buf][se0] = cvt8n(arf[0], arf[1]); \
      *(u16x8_t*)&sA[buf][se1] = cvt8n(arf[2], arf[3]); \
    } \
    *(u16x8_t*)&sB[buf][se0] = cvt8n(brf[0], brf[1]); \
    *(u16x8_t*)&sB[buf][se1] = cvt8n(brf[2], brf[3]); \
  } while (0)

  LOAD_T(0);
  STORE_T(0);
  int cur = 0;

  const int fswz = (lane & 7) << 3;
  const int kb   = (lane >> 4) * 8;
  const int fr   = lane & 15;

  for (int kt = 0; kt < 8; ++kt) {            // 512 / 64
    __syncthreads();                          // staged tile (cur) visible
    if (kt < 7) LOAD_T((kt + 1) * 64);        // next-tile global loads hide under MFMA
    #pragma unroll
    for (int kk = 0; kk < 64; kk += 32) {
      bf16x8_t af[4], bfv[2];
      #pragma unroll
      for (int i = 0; i < 4; ++i) {
        const int ra = wm * 64 + i * 16 + fr;
        af[i] = *(const bf16x8_t*)&sA[cur][ra * 64 + ((kk + kb) ^ ((ra & 7) << 3))];
      }
      #pragma unroll
      for (int j = 0; j < 2; ++j) {
        const int rb = wn * 32 + j * 16 + fr;
        bfv[j] = *(const bf16x8_t*)&sB[cur][rb * 64 + ((kk + kb) ^ ((rb & 7) << 3))];
      }
      #pragma unroll
      for (int i = 0; i < 4; ++i)
        #pragma unroll
        for (int j = 0; j < 2; ++j)
          acc[i][j] = __builtin_amdgcn_mfma_f32_16x16x32_bf16(af[i], bfv[j], acc[i][j], 0, 0, 0);
    }
    if (kt < 7) STORE_T(cur ^ 1);             // cvt + ds_write next buffer
    cur ^= 1;
  }
#undef LOAD_T
#undef STORE_T

  // Epilogue: D row = (lane>>4)*4 + r, col = lane&15  (m89-verified C/D layout)
  unsigned short* Cb = (unsigned short*)Cout + (size_t)z * NTOK * E_DIM;
  float* Cf = (float*)Cout;
  #pragma unroll
  for (int i = 0; i < 4; ++i) {
    const int row = (int)m0 + wm * 64 + i * 16 + (lane >> 4) * 4;
    #pragma unroll
    for (int j = 0; j < 2; ++j) {
      const int col = (int)n0 + wn * 32 + j * 16 + fr;
      const float bv = bz[col];
      #pragma unroll
      for (int r = 0; r < 4; ++r) {
        const float val = acc[i][j][r] + bv;
        if constexpr (OUT_BF16)
          Cb[(size_t)(row + r) * E_DIM + col] = (unsigned short)__builtin_bit_cast(unsigned short, (__bf16)val);
        else
          Cf[(size_t)(row + r) * E_DIM + col] = val;
      }
    }
  }
}

// ---------------- attention: gather projected rows, softmax over P=8, ctx (bf16) ----------------
__global__ __launch_bounds__(256)
void attn_kernel(const unsigned short* __restrict__ Qp, const unsigned short* __restrict__ Kp,
                 const unsigned short* __restrict__ Vp, const int* __restrict__ idx,
                 unsigned short* __restrict__ ctx)
{
  const int wid  = threadIdx.x >> 6;
  const int lane = threadIdx.x & 63;
  const int n = blockIdx.x * 4 + wid;
  const int b = n >> 11;
  const int h = lane >> 3;
  const int p = lane & 7;

  const int id = idx[n * 8 + p];
  const size_t krow = ((size_t)(b << 11) + id) * E_DIM + h * 64;
  const unsigned short* qb = Qp + (size_t)n * E_DIM + h * 64;

  float sc = 0.f;
  #pragma unroll
  for (int j = 0; j < 8; ++j) {
    u16x8_t qv = *(const u16x8_t*)(qb + j * 8);
    u16x8_t kv = *(const u16x8_t*)(Kp + krow + j * 8);
    #pragma unroll
    for (int e = 0; e < 8; ++e) sc += bf2f(qv[e]) * bf2f(kv[e]);
  }
  sc *= 0.125f;  // 1/sqrt(64)

  float m = sc;
  m = fmaxf(m, __shfl_xor(m, 1, 64));
  m = fmaxf(m, __shfl_xor(m, 2, 64));
  m = fmaxf(m, __shfl_xor(m, 4, 64));
  const float ex = __expf(sc - m);
  float dsum = ex;
  dsum += __shfl_xor(dsum, 1, 64);
  dsum += __shfl_xor(dsum, 2, 64);
  dsum += __shfl_xor(dsum, 4, 64);
  const float attn = ex / dsum;

  // phase 2: lane -> (h, d-block p*8); ctx[h][d] = sum_p attn[h][p] * Vp[idx_p][h*64+d]
  const int d0 = p * 8;
  float cacc[8];
  #pragma unroll
  for (int j = 0; j < 8; ++j) cacc[j] = 0.f;
  #pragma unroll
  for (int pp = 0; pp < 8; ++pp) {
    const float ap = __shfl(attn, (lane & 56) + pp, 64);
    const int  idp = __shfl(id,   (lane & 56) + pp, 64);
    const unsigned short* vb = Vp + ((size_t)(b << 11) + idp) * E_DIM + h * 64 + d0;
    u16x8_t vv = *(const u16x8_t*)vb;
    #pragma unroll
    for (int j = 0; j < 8; ++j) cacc[j] += ap * bf2f(vv[j]);
  }
  u16x8_t cc;
  #pragma unroll
  for (int j = 0; j < 8; ++j) cc[j] = __builtin_bit_cast(unsigned short, (__bf16)cacc[j]);
  *(u16x8_t*)(ctx + (size_t)n * E_DIM + h * 64 + d0) = cc;
}

extern "C" void kernel_launch(void* const* d_in, const int* in_sizes, int n_in,
                              void* d_out, int out_size, void* d_ws, size_t ws_size,
                              hipStream_t stream) {
  const float* q        = (const float*)d_in[0];
  const float* k        = (const float*)d_in[1];
  const float* v        = (const float*)d_in[2];
  const float* offset_w = (const float*)d_in[3];
  const float* offset_b = (const float*)d_in[4];
  const float* in_proj_w = (const float*)d_in[5];
  const float* in_proj_b = (const float*)d_in[6];
  const float* out_w    = (const float*)d_in[7];
  const float* out_b    = (const float*)d_in[8];

  char* ws = (char*)d_ws;
  // layout: Qp|Kp|Vp|ctx bf16 (4 * 16384*512*2 = 67.1MB), idx (512KB)
  unsigned short* Qp   = (unsigned short*)ws;
  unsigned short* Kp   = Qp + (size_t)NTOK * E_DIM;
  unsigned short* Vp   = Kp + (size_t)NTOK * E_DIM;
  unsigned short* ctxb = Vp + (size_t)NTOK * E_DIM;
  int* idxb = (int*)(ws + (size_t)4 * NTOK * E_DIM * 2);

  offsets_kernel<<<NTOK / 4, 256, 0, stream>>>(q, offset_w, offset_b, idxb);
  gemm_kernel<0, 1><<<dim3(NTOK / 128, E_DIM / 128, 3), 512, 0, stream>>>(
      q, k, v, in_proj_w, in_proj_b, (void*)Qp);
  attn_kernel<<<NTOK / 4, 256, 0, stream>>>(Qp, Kp, Vp, idxb, ctxb);
  gemm_kernel<1, 0><<<dim3(NTOK / 128, E_DIM / 128, 1), 512, 0, stream>>>(
      ctxb, ctxb, ctxb, out_w, out_b, d_out);
}

// Round 5
// 105.505 us; speedup vs baseline: 1.2852x; 1.1311x over previous
//
#include <hip/hip_runtime.h>

#define S_LEN 2048
#define E_DIM 512
#define NTOK  16384   // B*S = 8*2048

typedef __bf16 bf16x8_t __attribute__((ext_vector_type(8)));
typedef float f32x4_t __attribute__((ext_vector_type(4)));
typedef unsigned short u16x8_t __attribute__((ext_vector_type(8)));

__device__ __forceinline__ float bf2f(unsigned short h) {
  return __uint_as_float(((unsigned)h) << 16);
}
// native casts -> compiler emits v_cvt_pk_bf16_f32 (m240: don't hand-roll)
__device__ __forceinline__ u16x8_t cvt8n(float4 a, float4 b) {
  bf16x8_t t;
  t[0] = (__bf16)a.x; t[1] = (__bf16)a.y; t[2] = (__bf16)a.z; t[3] = (__bf16)a.w;
  t[4] = (__bf16)b.x; t[5] = (__bf16)b.y; t[6] = (__bf16)b.z; t[7] = (__bf16)b.w;
  union { bf16x8_t h; u16x8_t u; } cv; cv.h = t; return cv.u;
}
// async global->LDS, 16B per lane; LDS dest = wave-uniform base + lane*16
__device__ __forceinline__ void gload16(const void* g, void* l) {
  __builtin_amdgcn_global_load_lds(
      (const __attribute__((address_space(1))) unsigned int*)g,
      (__attribute__((address_space(3))) unsigned int*)l, 16, 0, 0);
}

// ---------------- offsets -> gather indices (fp32) + q -> bf16 side-product ----------------
__global__ __launch_bounds__(256)
void offsets_kernel(const float* __restrict__ q, const float* __restrict__ ow,
                    const float* __restrict__ ob, int* __restrict__ idx,
                    unsigned short* __restrict__ Qbf)
{
  const int wid  = threadIdx.x >> 6;
  const int lane = threadIdx.x & 63;
  const int n = blockIdx.x * 4 + wid;          // token
  const int s = n & (S_LEN - 1);
  const float* qr = q + (size_t)n * E_DIM + lane * 8;
  const float4 q0 = *(const float4*)qr;
  const float4 q1 = *(const float4*)(qr + 4);
  *(u16x8_t*)(Qbf + (size_t)n * E_DIM + lane * 8) = cvt8n(q0, q1);   // q -> bf16
  float myoff = 0.f;
  #pragma unroll
  for (int p = 0; p < 8; ++p) {
    const float* wr = ow + (size_t)(2 * p) * E_DIM + lane * 8;   // row 2p = offsets[...,0]
    const float4 w0 = *(const float4*)wr;
    const float4 w1 = *(const float4*)(wr + 4);
    float acc = q0.x*w0.x + q0.y*w0.y + q0.z*w0.z + q0.w*w0.w
              + q1.x*w1.x + q1.y*w1.y + q1.z*w1.z + q1.w*w1.w;
    #pragma unroll
    for (int d = 32; d; d >>= 1) acc += __shfl_xor(acc, d, 64);
    if ((lane & 7) == p) myoff = acc;
  }
  if (lane < 8) {
    float off = myoff + ob[2 * lane];
    float val = (float)s + off;
    int id = (int)truncf(val);                 // trunc toward zero, then clip (matches ref)
    id = id < 0 ? 0 : (id > S_LEN - 1 ? S_LEN - 1 : id);
    idx[n * 8 + lane] = id;
  }
}

// ---------------- bulk fp32 -> bf16 conversion: k, v, in_proj_w, out_w ----------------
__global__ __launch_bounds__(256)
void cvt_kernel(const float* __restrict__ k, const float* __restrict__ v,
                const float* __restrict__ ipw, const float* __restrict__ ow,
                unsigned short* __restrict__ Kb, unsigned short* __restrict__ Vb,
                unsigned short* __restrict__ Wb, unsigned short* __restrict__ OWb)
{
  const int bid = blockIdx.x;
  const float* src; unsigned short* dst; size_t off;
  if (bid < 4096)       { src = k;   dst = Kb;  off = (size_t)bid * 2048; }
  else if (bid < 8192)  { src = v;   dst = Vb;  off = (size_t)(bid - 4096) * 2048; }
  else if (bid < 8576)  { src = ipw; dst = Wb;  off = (size_t)(bid - 8192) * 2048; }
  else                  { src = ow;  dst = OWb; off = (size_t)(bid - 8576) * 2048; }
  const size_t i = off + (size_t)threadIdx.x * 8;
  const float4 a = *(const float4*)(src + i);
  const float4 b = *(const float4*)(src + i + 4);
  *(u16x8_t*)(dst + i) = cvt8n(a, b);
}

// ---------------- bf16 MFMA GEMM: C(16384 x 512) = A @ W^T + bias (all-bf16 inputs) ----------------
// 128x128 tile, BK=64, 4 waves (2x2) of 64x64 wave tiles, global_load_lds staging with
// pre-swizzled source (chunk ^= row&7 involution), 64 KB LDS dbuf -> 2 blocks/CU.
// Grid (m, n, z): same-m blocks 128 apart -> same XCD -> A L2-reuse.
template<int OUT_BF16>
__global__ __launch_bounds__(256, 2)
void gemm_kernel(const unsigned short* __restrict__ A0, const unsigned short* __restrict__ A1,
                 const unsigned short* __restrict__ A2, const unsigned short* __restrict__ W,
                 const float* __restrict__ bias, void* __restrict__ Cout)
{
  __shared__ __align__(16) unsigned short sA[2][128 * 64];
  __shared__ __align__(16) unsigned short sB[2][128 * 64];

  const int z = blockIdx.z;
  const unsigned short* A = (z == 0) ? A0 : ((z == 1) ? A1 : A2);
  const unsigned short* Wz = W + (size_t)z * E_DIM * E_DIM;
  const float* bz = bias + (size_t)z * E_DIM;

  const int t    = threadIdx.x;
  const int lane = t & 63;
  const int wid  = t >> 6;        // 0..3
  const int wm   = wid >> 1;      // 0..1
  const int wn   = wid & 1;       // 0..1
  const size_t m0 = (size_t)blockIdx.x * 128;
  const size_t n0 = (size_t)blockIdx.y * 128;

  // staging: wave wid owns rows [wid*32, wid*32+32); one gload16 = 8 rows (64 lanes x 16B).
  // lane -> row  = base + (lane>>3), chunk = lane&7. row&7 == lane>>3 always, so the
  // source swizzle chunk^(row&7) is the wave-constant (lane&7)^(lane>>3).
  const int srow0  = wid * 32;
  const int schunk = (lane & 7) ^ (lane >> 3);
  const unsigned short* gA = A  + (m0 + srow0 + (lane >> 3)) * E_DIM + schunk * 8;
  const unsigned short* gB = Wz + (n0 + srow0 + (lane >> 3)) * E_DIM + schunk * 8;

#define STAGE(buf, k0) do { \
    _Pragma("unroll") \
    for (int i_ = 0; i_ < 4; ++i_) { \
      gload16(gA + (size_t)(i_ * 8) * E_DIM + (k0), &sA[buf][(srow0 + i_ * 8) * 64]); \
      gload16(gB + (size_t)(i_ * 8) * E_DIM + (k0), &sB[buf][(srow0 + i_ * 8) * 64]); \
    } } while (0)

  f32x4_t acc[4][4];
  #pragma unroll
  for (int i = 0; i < 4; ++i)
    #pragma unroll
    for (int j = 0; j < 4; ++j)
      acc[i][j] = (f32x4_t){0.f, 0.f, 0.f, 0.f};

  STAGE(0, 0);
  int cur = 0;
  const int fr = lane & 15;
  const int ck0 = lane >> 4;      // fragment k-chunk base (0..3)

  for (int kt = 0; kt < 8; ++kt) {            // 512 / 64
    __syncthreads();                          // staged tile (cur) complete & visible
    if (kt < 7) STAGE(cur ^ 1, (kt + 1) * 64);
    #pragma unroll
    for (int kk = 0; kk < 64; kk += 32) {
      const int ckb = (kk >> 3) + ck0;        // 0..7
      bf16x8_t af[4], bfv[4];
      #pragma unroll
      for (int i = 0; i < 4; ++i) {
        const int ra = wm * 64 + i * 16 + fr;
        af[i] = *(const bf16x8_t*)&sA[cur][ra * 64 + ((ckb ^ (ra & 7)) << 3)];
      }
      #pragma unroll
      for (int j = 0; j < 4; ++j) {
        const int rb = wn * 64 + j * 16 + fr;
        bfv[j] = *(const bf16x8_t*)&sB[cur][rb * 64 + ((ckb ^ (rb & 7)) << 3)];
      }
      #pragma unroll
      for (int i = 0; i < 4; ++i)
        #pragma unroll
        for (int j = 0; j < 4; ++j)
          acc[i][j] = __builtin_amdgcn_mfma_f32_16x16x32_bf16(af[i], bfv[j], acc[i][j], 0, 0, 0);
    }
    cur ^= 1;
  }
#undef STAGE

  // Epilogue: D row = (lane>>4)*4 + r, col = lane&15  (m89-verified C/D layout)
  unsigned short* Cb = (unsigned short*)Cout + (size_t)z * NTOK * E_DIM;
  float* Cf = (float*)Cout;
  #pragma unroll
  for (int i = 0; i < 4; ++i) {
    const int row = (int)m0 + wm * 64 + i * 16 + (lane >> 4) * 4;
    #pragma unroll
    for (int j = 0; j < 4; ++j) {
      const int col = (int)n0 + wn * 64 + j * 16 + fr;
      const float bv = bz[col];
      #pragma unroll
      for (int r = 0; r < 4; ++r) {
        const float val = acc[i][j][r] + bv;
        if constexpr (OUT_BF16)
          Cb[(size_t)(row + r) * E_DIM + col] = __builtin_bit_cast(unsigned short, (__bf16)val);
        else
          Cf[(size_t)(row + r) * E_DIM + col] = val;
      }
    }
  }
}

// ---------------- attention: gather projected rows, softmax over P=8, ctx (bf16) ----------------
__global__ __launch_bounds__(256)
void attn_kernel(const unsigned short* __restrict__ Qp, const unsigned short* __restrict__ Kp,
                 const unsigned short* __restrict__ Vp, const int* __restrict__ idx,
                 unsigned short* __restrict__ ctx)
{
  const int wid  = threadIdx.x >> 6;
  const int lane = threadIdx.x & 63;
  const int n = blockIdx.x * 4 + wid;
  const int b = n >> 11;
  const int h = lane >> 3;
  const int p = lane & 7;

  const int id = idx[n * 8 + p];
  const size_t krow = ((size_t)(b << 11) + id) * E_DIM + h * 64;
  const unsigned short* qb = Qp + (size_t)n * E_DIM + h * 64;

  float sc = 0.f;
  #pragma unroll
  for (int j = 0; j < 8; ++j) {
    u16x8_t qv = *(const u16x8_t*)(qb + j * 8);
    u16x8_t kv = *(const u16x8_t*)(Kp + krow + j * 8);
    #pragma unroll
    for (int e = 0; e < 8; ++e) sc += bf2f(qv[e]) * bf2f(kv[e]);
  }
  sc *= 0.125f;  // 1/sqrt(64)

  float m = sc;
  m = fmaxf(m, __shfl_xor(m, 1, 64));
  m = fmaxf(m, __shfl_xor(m, 2, 64));
  m = fmaxf(m, __shfl_xor(m, 4, 64));
  const float ex = __expf(sc - m);
  float dsum = ex;
  dsum += __shfl_xor(dsum, 1, 64);
  dsum += __shfl_xor(dsum, 2, 64);
  dsum += __shfl_xor(dsum, 4, 64);
  const float attn = ex / dsum;

  // phase 2: lane -> (h, d-block p*8); ctx[h][d] = sum_p attn[h][p] * Vp[idx_p][h*64+d]
  const int d0 = p * 8;
  float cacc[8];
  #pragma unroll
  for (int j = 0; j < 8; ++j) cacc[j] = 0.f;
  #pragma unroll
  for (int pp = 0; pp < 8; ++pp) {
    const float ap = __shfl(attn, (lane & 56) + pp, 64);
    const int  idp = __shfl(id,   (lane & 56) + pp, 64);
    const unsigned short* vb = Vp + ((size_t)(b << 11) + idp) * E_DIM + h * 64 + d0;
    u16x8_t vv = *(const u16x8_t*)vb;
    #pragma unroll
    for (int j = 0; j < 8; ++j) cacc[j] += ap * bf2f(vv[j]);
  }
  u16x8_t cc;
  #pragma unroll
  for (int j = 0; j < 8; ++j) cc[j] = __builtin_bit_cast(unsigned short, (__bf16)cacc[j]);
  *(u16x8_t*)(ctx + (size_t)n * E_DIM + h * 64 + d0) = cc;
}

extern "C" void kernel_launch(void* const* d_in, const int* in_sizes, int n_in,
                              void* d_out, int out_size, void* d_ws, size_t ws_size,
                              hipStream_t stream) {
  const float* q        = (const float*)d_in[0];
  const float* k        = (const float*)d_in[1];
  const float* v        = (const float*)d_in[2];
  const float* offset_w = (const float*)d_in[3];
  const float* offset_b = (const float*)d_in[4];
  const float* in_proj_w = (const float*)d_in[5];
  const float* in_proj_b = (const float*)d_in[6];
  const float* out_w    = (const float*)d_in[7];
  const float* out_b    = (const float*)d_in[8];

  char* ws = (char*)d_ws;
  // ws layout (elements of u16):
  // Qbf | Kbf | Vbf | Wb(786432) | OWb(262144) | Qp | Kp | Vp | idx(int)
  // ctx aliases Qbf (dead after qkv GEMM). Total ~103 MB.
  unsigned short* Qbf = (unsigned short*)ws;
  unsigned short* Kbf = Qbf + (size_t)NTOK * E_DIM;
  unsigned short* Vbf = Kbf + (size_t)NTOK * E_DIM;
  unsigned short* Wb  = Vbf + (size_t)NTOK * E_DIM;
  unsigned short* OWb = Wb + (size_t)3 * E_DIM * E_DIM;
  unsigned short* Qp  = OWb + (size_t)E_DIM * E_DIM;
  unsigned short* Kp  = Qp + (size_t)NTOK * E_DIM;
  unsigned short* Vp  = Kp + (size_t)NTOK * E_DIM;
  int* idxb = (int*)(Vp + (size_t)NTOK * E_DIM);
  unsigned short* ctxb = Qbf;   // alias: Qbf dead after qkv GEMM

  offsets_kernel<<<NTOK / 4, 256, 0, stream>>>(q, offset_w, offset_b, idxb, Qbf);
  cvt_kernel<<<8704, 256, 0, stream>>>(k, v, in_proj_w, out_w, Kbf, Vbf, Wb, OWb);
  gemm_kernel<1><<<dim3(NTOK / 128, E_DIM / 128, 3), 256, 0, stream>>>(
      Qbf, Kbf, Vbf, Wb, in_proj_b, (void*)Qp);
  attn_kernel<<<NTOK / 4, 256, 0, stream>>>(Qp, Kp, Vp, idxb, ctxb);
  gemm_kernel<0><<<dim3(NTOK / 128, E_DIM / 128, 1), 256, 0, stream>>>(
      ctxb, ctxb, ctxb, OWb, out_b, d_out);
}